// Round 2
// baseline (502.705 us; speedup 1.0000x reference)
//
#include <hip/hip_runtime.h>

#define GAMMA 0.1f

typedef unsigned short u16;
typedef u16 u16x8 __attribute__((ext_vector_type(8)));
typedef short s16x8 __attribute__((ext_vector_type(8)));
typedef float f32x4 __attribute__((ext_vector_type(4)));

__device__ __forceinline__ float b2f(u16 u) {
  return __uint_as_float(((unsigned)u) << 16);
}
__device__ __forceinline__ u16 f2bf(float f) {
  unsigned u = __float_as_uint(f);
  unsigned r = (u + 0x7FFFu + ((u >> 16) & 1u)) >> 16;
  return (u16)r;
}

#define LDA 40
#define LDB 40

// -------- weight transpose + fp32->bf16: dst[n*K + k] = bf16(src[k*N + n]) --
__global__ __launch_bounds__(256) void transpose_k(
    const float* __restrict__ src, u16* __restrict__ dst, int K, int N)
{
  int idx = blockIdx.x * 256 + threadIdx.x;
  if (idx >= K * N) return;
  int nn = idx / K, kk = idx - nn * K;
  dst[idx] = f2bf(src[kk * N + nn]);
}

// -------- bias concat (fp32 passthrough) --------
__global__ __launch_bounds__(256) void bias_kernel(
    const float* __restrict__ bq, const float* __restrict__ bk,
    const float* __restrict__ bv, const float* __restrict__ bp1,
    const float* __restrict__ bo,
    float* __restrict__ biasQ, float* __restrict__ biasKVP,
    float* __restrict__ biasO)
{
  int i = blockIdx.x * 256 + threadIdx.x;
  if (i < 512) {
    biasQ[i] = bq[i];
  } else if (i < 1664) {
    int j = i - 512;
    float v;
    if (j < 512) v = bk[j];
    else if (j < 1024) v = bv[j - 512];
    else v = bp1[j - 1024];
    biasKVP[j] = v;
  } else if (i < 2176) {
    biasO[i - 1664] = bo[i - 1664];
  }
}

// -------- GEMM with gather-from-h A operand (A fp32 -> bf16 in staging) -----
// h layout: (bt=64, k=512, s=576) fp32. C: 36864 rows x NC bf16,
// row = (b*576+s)*16+t. WT: NC rows x 512 bf16 (k contiguous).
// Tile: BM=64 (s), BN=128 (cols), BK=32.
__global__ __launch_bounds__(256) void gemm_gather(
    const float* __restrict__ h, const u16* __restrict__ WT,
    const float* __restrict__ bias, u16* __restrict__ C, int NC)
{
  __shared__ __align__(16) u16 Al[64 * LDA];
  __shared__ __align__(16) u16 Bl[128 * LDB];
  const int tid = threadIdx.x;
  const int w = tid >> 6, lane = tid & 63;
  const int lhi = lane >> 4, llo = lane & 15;
  const int y = blockIdx.y;
  const int bt = y / 9, stile = y - bt * 9;
  const int s0 = stile * 64;
  const int col0 = blockIdx.x * 128;

  const float* Ab = h + (size_t)bt * (512 * 576) + s0;
  const u16* Bb = WT + (size_t)col0 * 512;

  const int ak = tid >> 3;          // 0..31 : k within tile
  const int aso = (tid & 7) * 8;    // s offset
  const int brow = tid >> 1;        // 0..127
  const int bko = (tid & 1) * 16;

  f32x4 acc[4][2];
#pragma unroll
  for (int mi = 0; mi < 4; ++mi)
#pragma unroll
    for (int ni = 0; ni < 2; ++ni)
#pragma unroll
      for (int e = 0; e < 4; ++e) acc[mi][ni][e] = 0.f;

  for (int kt = 0; kt < 16; ++kt) {
    __syncthreads();
    const float* ap = Ab + (size_t)(kt * 32 + ak) * 576 + aso;
    float4 a0 = *(const float4*)ap;
    float4 a1 = *(const float4*)(ap + 4);
    const u16* bp = Bb + brow * 512 + kt * 32 + bko;
    u16x8 bv0 = *(const u16x8*)bp;
    u16x8 bv1 = *(const u16x8*)(bp + 8);
    Al[(aso + 0) * LDA + ak] = f2bf(a0.x);   // transpose in LDS
    Al[(aso + 1) * LDA + ak] = f2bf(a0.y);
    Al[(aso + 2) * LDA + ak] = f2bf(a0.z);
    Al[(aso + 3) * LDA + ak] = f2bf(a0.w);
    Al[(aso + 4) * LDA + ak] = f2bf(a1.x);
    Al[(aso + 5) * LDA + ak] = f2bf(a1.y);
    Al[(aso + 6) * LDA + ak] = f2bf(a1.z);
    Al[(aso + 7) * LDA + ak] = f2bf(a1.w);
    *(u16x8*)&Bl[brow * LDB + bko] = bv0;
    *(u16x8*)&Bl[brow * LDB + bko + 8] = bv1;
    __syncthreads();

    s16x8 af[4], bf[2];
#pragma unroll
    for (int mi = 0; mi < 4; ++mi)
      af[mi] = *(const s16x8*)&Al[(mi * 16 + llo) * LDA + lhi * 8];
#pragma unroll
    for (int ni = 0; ni < 2; ++ni)
      bf[ni] = *(const s16x8*)&Bl[(w * 32 + ni * 16 + llo) * LDB + lhi * 8];
#pragma unroll
    for (int mi = 0; mi < 4; ++mi)
#pragma unroll
      for (int ni = 0; ni < 2; ++ni)
        acc[mi][ni] = __builtin_amdgcn_mfma_f32_16x16x32_bf16(
            af[mi], bf[ni], acc[mi][ni], 0, 0, 0);
  }

  const int b_ = bt >> 4, t_ = bt & 15;
  const size_t rowbase = (size_t)(b_ * 576 + s0) * 16 + t_;
  float bia0 = bias[col0 + w * 32 + llo];
  float bia1 = bias[col0 + w * 32 + 16 + llo];
#pragma unroll
  for (int mi = 0; mi < 4; ++mi) {
#pragma unroll
    for (int i = 0; i < 4; ++i) {
      const int m = mi * 16 + lhi * 4 + i;
      u16* cp = C + (rowbase + (size_t)m * 16) * NC + col0 + w * 32 + llo;
      cp[0]  = f2bf(acc[mi][0][i] + bia0);
      cp[16] = f2bf(acc[mi][1][i] + bia1);
    }
  }
}

// -------- penalty MLP tail: gelu -> dot(Wp2) -> sigmoid, one wave per row ----
__global__ __launch_bounds__(256) void pviol_kernel(
    const u16* __restrict__ KVP, const float* __restrict__ Wp2,
    const float* __restrict__ bp2, float* __restrict__ pv)
{
  const int tid = threadIdx.x;
  const int w = tid >> 6, lane = tid & 63;
  const int row = blockIdx.x * 4 + w;
  const int c = lane * 2;
  const u16* hp = KVP + (size_t)row * 1152 + 1024 + c;
  float x0 = b2f(hp[0]), x1 = b2f(hp[1]);
  float g0 = 0.5f * x0 * (1.f + erff(x0 * 0.70710678f));
  float g1 = 0.5f * x1 * (1.f + erff(x1 * 0.70710678f));
  float sum = g0 * Wp2[c] + g1 * Wp2[c + 1];
#pragma unroll
  for (int d = 1; d < 64; d <<= 1) sum += __shfl_xor(sum, d, 64);
  if (lane == 0) {
    float z = sum + bp2[0];
    pv[row] = 1.f / (1.f + expf(-z));
  }
}

// -------- attention: one wave per (n, head). att aliases Q (disjoint per wave).
__global__ __launch_bounds__(256) void attn_kernel(
    const u16* Q, const u16* __restrict__ KVP,
    const float* __restrict__ pviol, u16* att)
{
  __shared__ __align__(16) u16 Kl[4][16 * 72];
  __shared__ __align__(16) u16 Vl[4][16 * 72];
  __shared__ float Pl[4][16 * 17];
  const int tid = threadIdx.x;
  const int w = tid >> 6, lane = tid & 63;
  const int wid = blockIdx.x * 4 + w;
  const int n = wid >> 3, hh = wid & 7;
  const int g = lane >> 4, tq = lane & 15;

  // stage K,V 16x64 tiles
  const int r = lane >> 3, co = (lane & 7) * 8;
  const u16* Kb = KVP + (size_t)n * (16 * 1152) + hh * 64;
#pragma unroll
  for (int rr = 0; rr < 2; ++rr) {
    int row = r + rr * 8;
    *(u16x8*)&Kl[w][row * 72 + co] = *(const u16x8*)(Kb + row * 1152 + co);
    *(u16x8*)&Vl[w][row * 72 + co] = *(const u16x8*)(Kb + 512 + row * 1152 + co);
  }
  __syncthreads();

  // scores: lane (g,tq) computes s[tq][g*4+i]
  float s[4] = {0.f, 0.f, 0.f, 0.f};
  const u16* Qr = Q + ((size_t)n * 16 + tq) * 512 + hh * 64;
  for (int kc = 0; kc < 8; ++kc) {
    u16x8 q8 = *(const u16x8*)(Qr + kc * 8);
    float qf[8];
#pragma unroll
    for (int j = 0; j < 8; ++j) qf[j] = b2f(q8[j]);
#pragma unroll
    for (int i = 0; i < 4; ++i) {
      u16x8 k8 = *(const u16x8*)&Kl[w][(g * 4 + i) * 72 + kc * 8];
#pragma unroll
      for (int j = 0; j < 8; ++j) s[i] += qf[j] * b2f(k8[j]);
    }
  }

  const float* pv = pviol + n * 16;
#pragma unroll
  for (int i = 0; i < 4; ++i) s[i] = s[i] * 0.125f - GAMMA * pv[g * 4 + i];

  float mx = fmaxf(fmaxf(s[0], s[1]), fmaxf(s[2], s[3]));
  mx = fmaxf(mx, __shfl_xor(mx, 16, 64));
  mx = fmaxf(mx, __shfl_xor(mx, 32, 64));
  float e[4], sum = 0.f;
#pragma unroll
  for (int i = 0; i < 4; ++i) { e[i] = expf(s[i] - mx); sum += e[i]; }
  sum += __shfl_xor(sum, 16, 64);
  sum += __shfl_xor(sum, 32, 64);
  float inv = 1.f / sum;
#pragma unroll
  for (int i = 0; i < 4; ++i) Pl[w][tq * 17 + g * 4 + i] = e[i] * inv;
  __syncthreads();

  // out[tq][d], d in g*16..g*16+15
  float o[16];
#pragma unroll
  for (int j = 0; j < 16; ++j) o[j] = 0.f;
  for (int tk = 0; tk < 16; ++tk) {
    float p = Pl[w][tq * 17 + tk];
    u16x8 v0 = *(const u16x8*)&Vl[w][tk * 72 + g * 16];
    u16x8 v1 = *(const u16x8*)&Vl[w][tk * 72 + g * 16 + 8];
#pragma unroll
    for (int j = 0; j < 8; ++j) {
      o[j]     += p * b2f(v0[j]);
      o[8 + j] += p * b2f(v1[j]);
    }
  }
  u16* op = att + ((size_t)n * 16 + tq) * 512 + hh * 64 + g * 16;
  u16x8 r0, r1;
#pragma unroll
  for (int j = 0; j < 8; ++j) { r0[j] = f2bf(o[j]); r1[j] = f2bf(o[8 + j]); }
  *(u16x8*)op = r0;
  *(u16x8*)(op + 8) = r1;
}

// -------- output projection: bf16 A, fp32 out, LDS-transposed scatter -------
__global__ __launch_bounds__(256) void gemm_out(
    const u16* __restrict__ A, const u16* __restrict__ WT,
    const float* __restrict__ bias, float* __restrict__ out)
{
  __shared__ __align__(16) char smem[128 * 72 * 4];  // max(Al+Bl, Cl fp32)
  u16* Al = (u16*)smem;                    // 64 x LDA
  u16* Bl = (u16*)(smem + 64 * LDA * 2);   // 128 x LDB
  const int tid = threadIdx.x;
  const int w = tid >> 6, lane = tid & 63;
  const int lhi = lane >> 4, llo = lane & 15;
  const int y = blockIdx.y;
  const int bt = y / 9, stile = y - bt * 9;
  const int s0 = stile * 64;
  const int col0 = blockIdx.x * 128;
  const int b_ = bt >> 4, t_ = bt & 15;

  const u16* Ab = A + ((size_t)(b_ * 576 + s0) * 16 + t_) * 512;
  const u16* Bb = WT + (size_t)col0 * 512;

  const int am = tid >> 2;          // 0..63
  const int ako = (tid & 3) * 8;
  const int brow = tid >> 1;
  const int bko = (tid & 1) * 16;

  f32x4 acc[4][2];
#pragma unroll
  for (int mi = 0; mi < 4; ++mi)
#pragma unroll
    for (int ni = 0; ni < 2; ++ni)
#pragma unroll
      for (int e = 0; e < 4; ++e) acc[mi][ni][e] = 0.f;

  for (int kt = 0; kt < 16; ++kt) {
    __syncthreads();
    *(u16x8*)&Al[am * LDA + ako] =
        *(const u16x8*)(Ab + (size_t)am * (16 * 512) + kt * 32 + ako);
    const u16* bp = Bb + brow * 512 + kt * 32 + bko;
    *(u16x8*)&Bl[brow * LDB + bko] = *(const u16x8*)bp;
    *(u16x8*)&Bl[brow * LDB + bko + 8] = *(const u16x8*)(bp + 8);
    __syncthreads();

    s16x8 af[4], bf[2];
#pragma unroll
    for (int mi = 0; mi < 4; ++mi)
      af[mi] = *(const s16x8*)&Al[(mi * 16 + llo) * LDA + lhi * 8];
#pragma unroll
    for (int ni = 0; ni < 2; ++ni)
      bf[ni] = *(const s16x8*)&Bl[(w * 32 + ni * 16 + llo) * LDB + lhi * 8];
#pragma unroll
    for (int mi = 0; mi < 4; ++mi)
#pragma unroll
      for (int ni = 0; ni < 2; ++ni)
        acc[mi][ni] = __builtin_amdgcn_mfma_f32_16x16x32_bf16(
            af[mi], bf[ni], acc[mi][ni], 0, 0, 0);
  }

  __syncthreads();
  float* Cl = (float*)smem;  // 128 (n) x 72 (m, padded) fp32
  float bia0 = bias[col0 + w * 32 + llo];
  float bia1 = bias[col0 + w * 32 + 16 + llo];
#pragma unroll
  for (int mi = 0; mi < 4; ++mi)
#pragma unroll
    for (int i = 0; i < 4; ++i) {
      int m = mi * 16 + lhi * 4 + i;
      Cl[(w * 32 + llo) * 72 + m]      = acc[mi][0][i] + bia0;
      Cl[(w * 32 + 16 + llo) * 72 + m] = acc[mi][1][i] + bia1;
    }
  __syncthreads();
  const int nn = tid >> 1;
  const int mh = (tid & 1) * 32;
  const float* sp = Cl + nn * 72 + mh;
  float* dp = out + ((size_t)bt * 512 + col0 + nn) * 576 + s0 + mh;
#pragma unroll
  for (int j = 0; j < 8; ++j)
    *(float4*)(dp + j * 4) = *(const float4*)(sp + j * 4);
}

extern "C" void kernel_launch(void* const* d_in, const int* in_sizes, int n_in,
                              void* d_out, int out_size, void* d_ws, size_t ws_size,
                              hipStream_t stream)
{
  const float* h_opt = (const float*)d_in[0];
  const float* h_sar = (const float*)d_in[1];
  const float* Wq  = (const float*)d_in[2];
  const float* bq  = (const float*)d_in[3];
  const float* Wk  = (const float*)d_in[4];
  const float* bk  = (const float*)d_in[5];
  const float* Wv  = (const float*)d_in[6];
  const float* bv  = (const float*)d_in[7];
  const float* Wo  = (const float*)d_in[8];
  const float* bo  = (const float*)d_in[9];
  const float* Wp1 = (const float*)d_in[10];
  const float* bp1 = (const float*)d_in[11];
  const float* Wp2 = (const float*)d_in[12];
  const float* bp2 = (const float*)d_in[13];
  float* out = (float*)d_out;

  char* ws = (char*)d_ws;
  u16*   WqT     = (u16*)(ws + 0);          // 512x512 bf16   (524288 B)
  u16*   KVPW    = (u16*)(ws + 524288);     // 1152x512 bf16  (1179648 B)
  u16*   WoT     = (u16*)(ws + 1703936);    // 512x512 bf16   (524288 B)
  float* biasQ   = (float*)(ws + 2228224);  // 512 f32
  float* biasKVP = (float*)(ws + 2230272);  // 1152 f32
  float* biasO   = (float*)(ws + 2234880);  // 512 f32
  float* pviol   = (float*)(ws + 2236928);  // 36864 f32
  u16*   Qbuf    = (u16*)(ws + 2384384);    // 36864x512 bf16  — also att
  u16*   KVPbuf  = (u16*)(ws + 40133120);   // 36864x1152 bf16

  transpose_k<<<1024, 256, 0, stream>>>(Wq, WqT, 512, 512);
  transpose_k<<<1024, 256, 0, stream>>>(Wk, KVPW, 512, 512);
  transpose_k<<<1024, 256, 0, stream>>>(Wv, KVPW + 512 * 512, 512, 512);
  transpose_k<<<256, 256, 0, stream>>>(Wp1, KVPW + 1024 * 512, 512, 128);
  transpose_k<<<1024, 256, 0, stream>>>(Wo, WoT, 512, 512);
  bias_kernel<<<9, 256, 0, stream>>>(bq, bk, bv, bp1, bo, biasQ, biasKVP, biasO);

  gemm_gather<<<dim3(4, 576), 256, 0, stream>>>(h_opt, WqT, biasQ, Qbuf, 512);
  gemm_gather<<<dim3(9, 576), 256, 0, stream>>>(h_sar, KVPW, biasKVP, KVPbuf, 1152);
  pviol_kernel<<<9216, 256, 0, stream>>>(KVPbuf, Wp2, bp2, pviol);
  attn_kernel<<<4608, 256, 0, stream>>>(Qbuf, KVPbuf, pviol, Qbuf);
  gemm_out<<<dim3(4, 576), 256, 0, stream>>>(Qbuf, WoT, biasO, out);
}

// Round 3
// 480.428 us; speedup vs baseline: 1.0464x; 1.0464x over previous
//
#include <hip/hip_runtime.h>

#define GAMMA 0.1f

typedef unsigned short u16;
typedef u16 u16x8 __attribute__((ext_vector_type(8)));
typedef short s16x8 __attribute__((ext_vector_type(8)));
typedef float f32x4 __attribute__((ext_vector_type(4)));

__device__ __forceinline__ float b2f(u16 u) {
  return __uint_as_float(((unsigned)u) << 16);
}
__device__ __forceinline__ u16 f2bf(float f) {
  unsigned u = __float_as_uint(f);
  unsigned r = (u + 0x7FFFu + ((u >> 16) & 1u)) >> 16;
  return (u16)r;
}

// async global->LDS, 16B per lane; lds base must be wave-uniform, HW adds lane*16
__device__ __forceinline__ void gl2lds16(const u16* g, u16* l) {
  __builtin_amdgcn_global_load_lds(
      (const __attribute__((address_space(1))) unsigned int*)g,
      (__attribute__((address_space(3))) unsigned int*)l, 16, 0, 0);
}

// -------- weight transpose + fp32->bf16: dst[n*K + k] = bf16(src[k*N + n]) --
__global__ __launch_bounds__(256) void transpose_k(
    const float* __restrict__ src, u16* __restrict__ dst, int K, int N)
{
  int idx = blockIdx.x * 256 + threadIdx.x;
  if (idx >= K * N) return;
  int nn = idx / K, kk = idx - nn * K;
  dst[idx] = f2bf(src[kk * N + nn]);
}

// -------- bias concat (fp32 passthrough) --------
__global__ __launch_bounds__(256) void bias_kernel(
    const float* __restrict__ bq, const float* __restrict__ bk,
    const float* __restrict__ bv, const float* __restrict__ bp1,
    const float* __restrict__ bo,
    float* __restrict__ biasQ, float* __restrict__ biasKVP,
    float* __restrict__ biasO)
{
  int i = blockIdx.x * 256 + threadIdx.x;
  if (i < 512) {
    biasQ[i] = bq[i];
  } else if (i < 1664) {
    int j = i - 512;
    float v;
    if (j < 512) v = bk[j];
    else if (j < 1024) v = bv[j - 512];
    else v = bp1[j - 1024];
    biasKVP[j] = v;
  } else if (i < 2176) {
    biasO[i - 1664] = bo[i - 1664];
  }
}

// -------- GEMM with gather-from-h A operand (A fp32 -> bf16 in staging) -----
// h layout: (bt=64, k=512, s=576) fp32. C: 36864 rows x NC bf16,
// row = (b*576+s)*16+t. WT: NC rows x 512 bf16 (k contiguous).
// Tile: BM=64 (s), BN=128 (cols), BK=32.
// A LDS layout: addr(row,k) = row*32 + ((k>>3) ^ ((row>>3)&3))*8 + (k&7)
//   -> scalar transpose writes are ~2-way (free); b128 reads are min-phase.
// B staged via global_load_lds (LDB=32, lane-linear).
__global__ __launch_bounds__(256) void gemm_gather(
    const float* __restrict__ h, const u16* __restrict__ WT,
    const float* __restrict__ bias, u16* __restrict__ C, int NC)
{
  __shared__ __align__(16) u16 Al[64 * 32];
  __shared__ __align__(16) u16 Bl[128 * 32];
  const int tid = threadIdx.x;
  const int w = tid >> 6, lane = tid & 63;
  const int lhi = lane >> 4, llo = lane & 15;
  const int y = blockIdx.y;
  const int bt = y / 9, stile = y - bt * 9;
  const int s0 = stile * 64;
  const int col0 = blockIdx.x * 128;

  const float* Ab = h + (size_t)bt * (512 * 576) + s0;
  const u16* Bb = WT + (size_t)col0 * 512;

  const int ak = tid >> 3;          // 0..31 : k within tile
  const int aso = (tid & 7) * 8;    // s row base
  const int ae = ak & 7;            // element within 8-chunk
  const int ac = ak >> 3;           // chunk (wave-uniform)

  // B stage addressing (per wave: 2 calls of 1024B)
  const int q0 = w * 2, q1 = w * 2 + 1;
  const int bko = (lane & 3) * 8;
  const int br0 = q0 * 16 + (lane >> 2);
  const int br1 = q1 * 16 + (lane >> 2);

  f32x4 acc[4][2];
#pragma unroll
  for (int mi = 0; mi < 4; ++mi)
#pragma unroll
    for (int ni = 0; ni < 2; ++ni)
#pragma unroll
      for (int e = 0; e < 4; ++e) acc[mi][ni][e] = 0.f;

  for (int kt = 0; kt < 16; ++kt) {
    __syncthreads();
    // B: async direct-to-LDS
    gl2lds16(Bb + (size_t)br0 * 512 + kt * 32 + bko, &Bl[q0 * 512]);
    gl2lds16(Bb + (size_t)br1 * 512 + kt * 32 + bko, &Bl[q1 * 512]);
    // A: coalesced fp32 loads, swizzled bf16 transpose into LDS
    const float* ap = Ab + (size_t)(kt * 32 + ak) * 576 + aso;
    float4 a0 = *(const float4*)ap;
    float4 a1 = *(const float4*)(ap + 4);
    float av[8] = {a0.x, a0.y, a0.z, a0.w, a1.x, a1.y, a1.z, a1.w};
#pragma unroll
    for (int i = 0; i < 8; ++i) {
      int row = aso + i;
      int cs = ac ^ ((row >> 3) & 3);
      Al[row * 32 + cs * 8 + ae] = f2bf(av[i]);
    }
    __syncthreads();

    s16x8 af[4], bfr[2];
#pragma unroll
    for (int mi = 0; mi < 4; ++mi) {
      int row = mi * 16 + llo;
      int cs = lhi ^ ((row >> 3) & 3);
      af[mi] = *(const s16x8*)&Al[row * 32 + cs * 8];
    }
#pragma unroll
    for (int ni = 0; ni < 2; ++ni)
      bfr[ni] = *(const s16x8*)&Bl[(w * 32 + ni * 16 + llo) * 32 + lhi * 8];
#pragma unroll
    for (int mi = 0; mi < 4; ++mi)
#pragma unroll
      for (int ni = 0; ni < 2; ++ni)
        acc[mi][ni] = __builtin_amdgcn_mfma_f32_16x16x32_bf16(
            af[mi], bfr[ni], acc[mi][ni], 0, 0, 0);
  }

  const int b_ = bt >> 4, t_ = bt & 15;
  const size_t rowbase = (size_t)(b_ * 576 + s0) * 16 + t_;
  float bia0 = bias[col0 + w * 32 + llo];
  float bia1 = bias[col0 + w * 32 + 16 + llo];
#pragma unroll
  for (int mi = 0; mi < 4; ++mi) {
#pragma unroll
    for (int i = 0; i < 4; ++i) {
      const int m = mi * 16 + lhi * 4 + i;
      u16* cp = C + (rowbase + (size_t)m * 16) * NC + col0 + w * 32 + llo;
      cp[0]  = f2bf(acc[mi][0][i] + bia0);
      cp[16] = f2bf(acc[mi][1][i] + bia1);
    }
  }
}

// -------- penalty MLP tail: gelu -> dot(Wp2) -> sigmoid, one wave per row ----
__global__ __launch_bounds__(256) void pviol_kernel(
    const u16* __restrict__ KVP, const float* __restrict__ Wp2,
    const float* __restrict__ bp2, float* __restrict__ pv)
{
  const int tid = threadIdx.x;
  const int w = tid >> 6, lane = tid & 63;
  const int row = blockIdx.x * 4 + w;
  const int c = lane * 2;
  const u16* hp = KVP + (size_t)row * 1152 + 1024 + c;
  float x0 = b2f(hp[0]), x1 = b2f(hp[1]);
  float g0 = 0.5f * x0 * (1.f + erff(x0 * 0.70710678f));
  float g1 = 0.5f * x1 * (1.f + erff(x1 * 0.70710678f));
  float sum = g0 * Wp2[c] + g1 * Wp2[c + 1];
#pragma unroll
  for (int d = 1; d < 64; d <<= 1) sum += __shfl_xor(sum, d, 64);
  if (lane == 0) {
    float z = sum + bp2[0];
    pv[row] = 1.f / (1.f + expf(-z));
  }
}

// -------- attention: one wave per (n, head). att aliases Q (disjoint per wave).
__global__ __launch_bounds__(256) void attn_kernel(
    const u16* Q, const u16* __restrict__ KVP,
    const float* __restrict__ pviol, u16* att)
{
  __shared__ __align__(16) u16 Kl[4][16 * 72];
  __shared__ __align__(16) u16 Vl[4][16 * 72];
  __shared__ float Pl[4][16 * 17];
  const int tid = threadIdx.x;
  const int w = tid >> 6, lane = tid & 63;
  const int wid = blockIdx.x * 4 + w;
  const int n = wid >> 3, hh = wid & 7;
  const int g = lane >> 4, tq = lane & 15;

  // stage K,V 16x64 tiles
  const int r = lane >> 3, co = (lane & 7) * 8;
  const u16* Kb = KVP + (size_t)n * (16 * 1152) + hh * 64;
#pragma unroll
  for (int rr = 0; rr < 2; ++rr) {
    int row = r + rr * 8;
    *(u16x8*)&Kl[w][row * 72 + co] = *(const u16x8*)(Kb + row * 1152 + co);
    *(u16x8*)&Vl[w][row * 72 + co] = *(const u16x8*)(Kb + 512 + row * 1152 + co);
  }
  __syncthreads();

  // scores: lane (g,tq) computes s[tq][g*4+i]
  float s[4] = {0.f, 0.f, 0.f, 0.f};
  const u16* Qr = Q + ((size_t)n * 16 + tq) * 512 + hh * 64;
  for (int kc = 0; kc < 8; ++kc) {
    u16x8 q8 = *(const u16x8*)(Qr + kc * 8);
    float qf[8];
#pragma unroll
    for (int j = 0; j < 8; ++j) qf[j] = b2f(q8[j]);
#pragma unroll
    for (int i = 0; i < 4; ++i) {
      u16x8 k8 = *(const u16x8*)&Kl[w][(g * 4 + i) * 72 + kc * 8];
#pragma unroll
      for (int j = 0; j < 8; ++j) s[i] += qf[j] * b2f(k8[j]);
    }
  }

  const float* pv = pviol + n * 16;
#pragma unroll
  for (int i = 0; i < 4; ++i) s[i] = s[i] * 0.125f - GAMMA * pv[g * 4 + i];

  float mx = fmaxf(fmaxf(s[0], s[1]), fmaxf(s[2], s[3]));
  mx = fmaxf(mx, __shfl_xor(mx, 16, 64));
  mx = fmaxf(mx, __shfl_xor(mx, 32, 64));
  float e[4], sum = 0.f;
#pragma unroll
  for (int i = 0; i < 4; ++i) { e[i] = expf(s[i] - mx); sum += e[i]; }
  sum += __shfl_xor(sum, 16, 64);
  sum += __shfl_xor(sum, 32, 64);
  float inv = 1.f / sum;
#pragma unroll
  for (int i = 0; i < 4; ++i) Pl[w][tq * 17 + g * 4 + i] = e[i] * inv;
  __syncthreads();

  // out[tq][d], d in g*16..g*16+15
  float o[16];
#pragma unroll
  for (int j = 0; j < 16; ++j) o[j] = 0.f;
  for (int tk = 0; tk < 16; ++tk) {
    float p = Pl[w][tq * 17 + tk];
    u16x8 v0 = *(const u16x8*)&Vl[w][tk * 72 + g * 16];
    u16x8 v1 = *(const u16x8*)&Vl[w][tk * 72 + g * 16 + 8];
#pragma unroll
    for (int j = 0; j < 8; ++j) {
      o[j]     += p * b2f(v0[j]);
      o[8 + j] += p * b2f(v1[j]);
    }
  }
  u16* op = att + ((size_t)n * 16 + tq) * 512 + hh * 64 + g * 16;
  u16x8 r0, r1;
#pragma unroll
  for (int j = 0; j < 8; ++j) { r0[j] = f2bf(o[j]); r1[j] = f2bf(o[8 + j]); }
  *(u16x8*)op = r0;
  *(u16x8*)(op + 8) = r1;
}

// -------- output projection: bf16 A (row-major), fp32 out ------------------
// A and B both staged via global_load_lds, LDA=LDB=32 (min-phase b128 reads).
__global__ __launch_bounds__(256) void gemm_out(
    const u16* __restrict__ A, const u16* __restrict__ WT,
    const float* __restrict__ bias, float* __restrict__ out)
{
  __shared__ __align__(16) char smem[128 * 72 * 4];  // >= Al+Bl; Cl fp32 epilogue
  u16* Al = (u16*)smem;                    // 64 x 32
  u16* Bl = (u16*)(smem + 64 * 32 * 2);    // 128 x 32
  const int tid = threadIdx.x;
  const int w = tid >> 6, lane = tid & 63;
  const int lhi = lane >> 4, llo = lane & 15;
  const int y = blockIdx.y;
  const int bt = y / 9, stile = y - bt * 9;
  const int s0 = stile * 64;
  const int col0 = blockIdx.x * 128;
  const int b_ = bt >> 4, t_ = bt & 15;

  const u16* Ab = A + ((size_t)(b_ * 576 + s0) * 16 + t_) * 512;
  const u16* Bb = WT + (size_t)col0 * 512;

  // A stage: 1 call/wave (1024B); lane element = w*512 + lane*8
  const int arow = w * 16 + (lane >> 2);   // m row (s index)
  const int ako = (lane & 3) * 8;
  // B stage: 2 calls/wave
  const int q0 = w * 2, q1 = w * 2 + 1;
  const int br0 = q0 * 16 + (lane >> 2);
  const int br1 = q1 * 16 + (lane >> 2);

  f32x4 acc[4][2];
#pragma unroll
  for (int mi = 0; mi < 4; ++mi)
#pragma unroll
    for (int ni = 0; ni < 2; ++ni)
#pragma unroll
      for (int e = 0; e < 4; ++e) acc[mi][ni][e] = 0.f;

  for (int kt = 0; kt < 16; ++kt) {
    __syncthreads();
    gl2lds16(Ab + (size_t)arow * (16 * 512) + kt * 32 + ako, &Al[w * 512]);
    gl2lds16(Bb + (size_t)br0 * 512 + kt * 32 + ako, &Bl[q0 * 512]);
    gl2lds16(Bb + (size_t)br1 * 512 + kt * 32 + ako, &Bl[q1 * 512]);
    __syncthreads();

    s16x8 af[4], bfr[2];
#pragma unroll
    for (int mi = 0; mi < 4; ++mi)
      af[mi] = *(const s16x8*)&Al[(mi * 16 + llo) * 32 + lhi * 8];
#pragma unroll
    for (int ni = 0; ni < 2; ++ni)
      bfr[ni] = *(const s16x8*)&Bl[(w * 32 + ni * 16 + llo) * 32 + lhi * 8];
#pragma unroll
    for (int mi = 0; mi < 4; ++mi)
#pragma unroll
      for (int ni = 0; ni < 2; ++ni)
        acc[mi][ni] = __builtin_amdgcn_mfma_f32_16x16x32_bf16(
            af[mi], bfr[ni], acc[mi][ni], 0, 0, 0);
  }

  __syncthreads();
  float* Cl = (float*)smem;  // 128 (n) x 72 (m, padded) fp32
  float bia0 = bias[col0 + w * 32 + llo];
  float bia1 = bias[col0 + w * 32 + 16 + llo];
#pragma unroll
  for (int mi = 0; mi < 4; ++mi)
#pragma unroll
    for (int i = 0; i < 4; ++i) {
      int m = mi * 16 + lhi * 4 + i;
      Cl[(w * 32 + llo) * 72 + m]      = acc[mi][0][i] + bia0;
      Cl[(w * 32 + 16 + llo) * 72 + m] = acc[mi][1][i] + bia1;
    }
  __syncthreads();
  const int nn = tid >> 1;
  const int mh = (tid & 1) * 32;
  const float* sp = Cl + nn * 72 + mh;
  float* dp = out + ((size_t)bt * 512 + col0 + nn) * 576 + s0 + mh;
#pragma unroll
  for (int j = 0; j < 8; ++j)
    *(float4*)(dp + j * 4) = *(const float4*)(sp + j * 4);
}

extern "C" void kernel_launch(void* const* d_in, const int* in_sizes, int n_in,
                              void* d_out, int out_size, void* d_ws, size_t ws_size,
                              hipStream_t stream)
{
  const float* h_opt = (const float*)d_in[0];
  const float* h_sar = (const float*)d_in[1];
  const float* Wq  = (const float*)d_in[2];
  const float* bq  = (const float*)d_in[3];
  const float* Wk  = (const float*)d_in[4];
  const float* bk  = (const float*)d_in[5];
  const float* Wv  = (const float*)d_in[6];
  const float* bv  = (const float*)d_in[7];
  const float* Wo  = (const float*)d_in[8];
  const float* bo  = (const float*)d_in[9];
  const float* Wp1 = (const float*)d_in[10];
  const float* bp1 = (const float*)d_in[11];
  const float* Wp2 = (const float*)d_in[12];
  const float* bp2 = (const float*)d_in[13];
  float* out = (float*)d_out;

  char* ws = (char*)d_ws;
  u16*   WqT     = (u16*)(ws + 0);          // 512x512 bf16   (524288 B)
  u16*   KVPW    = (u16*)(ws + 524288);     // 1152x512 bf16  (1179648 B)
  u16*   WoT     = (u16*)(ws + 1703936);    // 512x512 bf16   (524288 B)
  float* biasQ   = (float*)(ws + 2228224);  // 512 f32
  float* biasKVP = (float*)(ws + 2230272);  // 1152 f32
  float* biasO   = (float*)(ws + 2234880);  // 512 f32
  float* pviol   = (float*)(ws + 2236928);  // 36864 f32
  u16*   Qbuf    = (u16*)(ws + 2384384);    // 36864x512 bf16  — also att
  u16*   KVPbuf  = (u16*)(ws + 40133120);   // 36864x1152 bf16

  transpose_k<<<1024, 256, 0, stream>>>(Wq, WqT, 512, 512);
  transpose_k<<<1024, 256, 0, stream>>>(Wk, KVPW, 512, 512);
  transpose_k<<<1024, 256, 0, stream>>>(Wv, KVPW + 512 * 512, 512, 512);
  transpose_k<<<256, 256, 0, stream>>>(Wp1, KVPW + 1024 * 512, 512, 128);
  transpose_k<<<1024, 256, 0, stream>>>(Wo, WoT, 512, 512);
  bias_kernel<<<9, 256, 0, stream>>>(bq, bk, bv, bp1, bo, biasQ, biasKVP, biasO);

  gemm_gather<<<dim3(4, 576), 256, 0, stream>>>(h_opt, WqT, biasQ, Qbuf, 512);
  gemm_gather<<<dim3(9, 576), 256, 0, stream>>>(h_sar, KVPW, biasKVP, KVPbuf, 1152);
  pviol_kernel<<<9216, 256, 0, stream>>>(KVPbuf, Wp2, bp2, pviol);
  attn_kernel<<<4608, 256, 0, stream>>>(Qbuf, KVPbuf, pviol, Qbuf);
  gemm_out<<<dim3(4, 576), 256, 0, stream>>>(Qbuf, WoT, biasO, out);
}